// Round 9
// baseline (361.631 us; speedup 1.0000x reference)
//
#include <hip/hip_runtime.h>
#include <stdint.h>

// Problem constants (reference: B=2, S=2048, D=1024, H=16, DK=64)
#define B_  2
#define S_  2048
#define D_  1024
#define H_  16
#define DK_ 64
#define PERHEAD (S_ * DK_)  // 131072 elems per (b,h)

// exp(x*0.125) = exp2(x * 0.125*log2(e))
#define EXP2SCALE 0.18033688011112042f

typedef __attribute__((ext_vector_type(8))) short short8;     // 8 bf16 (MFMA K=32 A/B frag)
typedef __attribute__((ext_vector_type(4))) float floatx4;    // MFMA C/D frag
typedef __fp16 fp16x2 __attribute__((ext_vector_type(2)));    // cvt_pkrtz result type
typedef _Float16 half4_t __attribute__((ext_vector_type(4))); // MFMA K=16 f16 A/B frag

#define MFMA16(a, b, c)   __builtin_amdgcn_mfma_f32_16x16x32_bf16((a), (b), (c), 0, 0, 0)
#define MFMA16H(a, b, c)  __builtin_amdgcn_mfma_f32_16x16x16f16((a), (b), (c), 0, 0, 0)

// async global->LDS, 16B per lane (used only in the projection GEMMs)
__device__ __forceinline__ void gload_lds16(const void* g, void* lds) {
  __builtin_amdgcn_global_load_lds(
      (__attribute__((address_space(1))) void*)(void*)g,
      (__attribute__((address_space(3))) void*)lds, 16, 0, 0);
}

__device__ __forceinline__ unsigned short f2bf(float f) {
  union { float f; unsigned int u; } v;
  v.f = f;
  unsigned int r = v.u + 0x7fffu + ((v.u >> 16) & 1u);
  return (unsigned short)(r >> 16);
}

// pack two f32 into two bf16 (round-half-up via +0x8000, hi16 via v_perm)
__device__ __forceinline__ unsigned int pack_bf16_rhu(float e0, float e1) {
  unsigned int u0 = __float_as_uint(e0) + 0x8000u;
  unsigned int u1 = __float_as_uint(e1) + 0x8000u;
  return __builtin_amdgcn_perm(u1, u0, 0x07060302);  // {u1.hi16, u0.hi16}
}

// ---------------- batched casts fp32 -> bf16 ----------------
__global__ void cast3_f32_bf16(const float* __restrict__ a0, const float* __restrict__ a1,
                               const float* __restrict__ a2,
                               unsigned short* __restrict__ o0, unsigned short* __restrict__ o1,
                               unsigned short* __restrict__ o2, int n4) {
  const float* in = (blockIdx.z == 0) ? a0 : (blockIdx.z == 1) ? a1 : a2;
  unsigned short* out = (blockIdx.z == 0) ? o0 : (blockIdx.z == 1) ? o1 : o2;
  int i = blockIdx.x * 256 + threadIdx.x;
  if (i < n4) {
    float4 f = ((const float4*)in)[i];
    uint2 p;
    p.x = (unsigned int)f2bf(f.x) | ((unsigned int)f2bf(f.y) << 16);
    p.y = (unsigned int)f2bf(f.z) | ((unsigned int)f2bf(f.w) << 16);
    ((uint2*)out)[i] = p;
  }
}
__global__ void cast4_f32_bf16(const float* __restrict__ a0, const float* __restrict__ a1,
                               const float* __restrict__ a2, const float* __restrict__ a3,
                               unsigned short* __restrict__ o0, unsigned short* __restrict__ o1,
                               unsigned short* __restrict__ o2, unsigned short* __restrict__ o3,
                               int n4) {
  const float* in = (blockIdx.z == 0) ? a0 : (blockIdx.z == 1) ? a1 : (blockIdx.z == 2) ? a2 : a3;
  unsigned short* out = (blockIdx.z == 0) ? o0 : (blockIdx.z == 1) ? o1 : (blockIdx.z == 2) ? o2 : o3;
  int i = blockIdx.x * 256 + threadIdx.x;
  if (i < n4) {
    float4 f = ((const float4*)in)[i];
    uint2 p;
    p.x = (unsigned int)f2bf(f.x) | ((unsigned int)f2bf(f.y) << 16);
    p.y = (unsigned int)f2bf(f.z) | ((unsigned int)f2bf(f.w) << 16);
    ((uint2*)out)[i] = p;
  }
}

// Layouts:
// Qf/Kf (bf16, K=32 frags) per (b,h): frag(sblk=s>>4, ks=dk>>5): idx = sblk*2+ks;
//   lane L holds [row=L&15][k=(L>>4)*8+j] as 16B chunk at frag*512 + L*8.
// Vg (f16, K=16 B-frags) per (b,h): frag f = (key>>4)*4 + (dk>>4); lane L holds
//   V[key=(f>>2)*16+(L>>4)*4+j][dk=(f&3)*16+(L&15)], 4 f16 = 8B at f*256 + L*4 (ushorts).

// ---------------- shared GEMM core: 128x128 tile, BK=32, 4 waves each 64x64 ----------
__device__ __forceinline__ void gemm_core(const unsigned short* __restrict__ A,
                                          const unsigned short* __restrict__ Bw,
                                          unsigned short* lA, unsigned short* lB,
                                          int m0, int n0, int tid, int lane, int wave,
                                          floatx4 acc[4][4]) {
  const int wm = (wave >> 1) * 64;
  const int wn = (wave & 1) * 64;
  for (int k0 = 0; k0 < D_; k0 += 32) {
#pragma unroll
    for (int l = 0; l < 2; ++l) {
      int c = l * 256 + tid;
      int row = c >> 2, cb = (c & 3) * 16;
      const char* ga = (const char*)A + ((size_t)(m0 + row) * D_ + k0) * 2 + cb;
      gload_lds16(ga, (char*)lA + (size_t)(l * 256 + wave * 64) * 16);
      const char* gb = (const char*)Bw + ((size_t)(n0 + row) * D_ + k0) * 2 + cb;
      gload_lds16(gb, (char*)lB + (size_t)(l * 256 + wave * 64) * 16);
    }
    __syncthreads();
    short8 af[4], bf_[4];
#pragma unroll
    for (int mt = 0; mt < 4; ++mt)
      af[mt] = *(const short8*)&lA[(wm + mt * 16 + (lane & 15)) * 32 + (lane >> 4) * 8];
#pragma unroll
    for (int nt = 0; nt < 4; ++nt)
      bf_[nt] = *(const short8*)&lB[(wn + nt * 16 + (lane & 15)) * 32 + (lane >> 4) * 8];
#pragma unroll
    for (int mt = 0; mt < 4; ++mt)
#pragma unroll
      for (int nt = 0; nt < 4; ++nt)
        acc[mt][nt] = MFMA16(af[mt], bf_[nt], acc[mt][nt]);
    __syncthreads();
  }
}

// ---------------- fused QKV projection: z selects (A, W, Out, epilogue) ----------------
__launch_bounds__(256, 2)
__global__ void gemm_qkv(const unsigned short* __restrict__ qi, const unsigned short* __restrict__ ki,
                         const unsigned short* __restrict__ vi,
                         const unsigned short* __restrict__ Wq, const unsigned short* __restrict__ Wk,
                         const unsigned short* __restrict__ Wv,
                         unsigned short* __restrict__ Qf, unsigned short* __restrict__ Kf,
                         unsigned short* __restrict__ Vg) {
  __shared__ unsigned short lA[128 * 32];
  __shared__ unsigned short lB[128 * 32];
  const int z = blockIdx.z;
  const unsigned short* A  = (z == 0) ? qi : (z == 1) ? ki : vi;
  const unsigned short* Bw = (z == 0) ? Wq : (z == 1) ? Wk : Wv;
  unsigned short* O        = (z == 0) ? Qf : (z == 1) ? Kf : Vg;
  const int tid = threadIdx.x, lane = tid & 63, wave = tid >> 6;
  const int m0 = blockIdx.y * 128, n0 = blockIdx.x * 128;
  const int wm = (wave >> 1) * 64, wn = (wave & 1) * 64;

  floatx4 acc[4][4] = {};
  gemm_core(A, Bw, lA, lB, m0, n0, tid, lane, wave, acc);

  if (z < 2) {  // Qf/Kf bf16 K=32 fragment layout
#pragma unroll
    for (int mt = 0; mt < 4; ++mt)
#pragma unroll
      for (int nt = 0; nt < 4; ++nt)
#pragma unroll
        for (int r = 0; r < 4; ++r) {
          int row = m0 + wm + mt * 16 + (lane >> 4) * 4 + r;  // token
          int col = n0 + wn + nt * 16 + (lane & 15);          // e
          int b = row >> 11, s = row & (S_ - 1);
          int h = col >> 6,  dk = col & 63;
          size_t base = (size_t)(b * H_ + h) * PERHEAD;
          int frag = (s >> 4) * 2 + (dk >> 5);
          int lp = (s & 15) | (((dk >> 3) & 3) << 4);
          O[base + (size_t)frag * 512 + lp * 8 + (dk & 7)] = f2bf(acc[mt][nt][r]);
        }
  } else {  // Vg f16 K=16 B-fragment layout
#pragma unroll
    for (int mt = 0; mt < 4; ++mt)
#pragma unroll
      for (int nt = 0; nt < 4; ++nt) {
        int row0 = m0 + wm + mt * 16 + (lane >> 4) * 4;  // 4 consecutive keys
        int col  = n0 + wn + nt * 16 + (lane & 15);
        int b = row0 >> 11, key0 = row0 & (S_ - 1);
        int h = col >> 6,   dk = col & 63;
        size_t base = (size_t)(b * H_ + h) * PERHEAD;
        int f = (key0 >> 4) * 4 + (dk >> 4);
        int lp = (dk & 15) | (((key0 >> 2) & 3) << 4);
        union { fp16x2 h2[2]; uint2 u; } pk;
        pk.h2[0] = __builtin_amdgcn_cvt_pkrtz(acc[mt][nt][0], acc[mt][nt][1]);
        pk.h2[1] = __builtin_amdgcn_cvt_pkrtz(acc[mt][nt][2], acc[mt][nt][3]);
        *(uint2*)&O[base + (size_t)f * 256 + lp * 4] = pk.u;
      }
  }
}

// ---------------- output projection: fp32 row-major ----------------
__launch_bounds__(256, 2)
__global__ void gemm_out(const unsigned short* __restrict__ A, const unsigned short* __restrict__ Bw,
                         float* __restrict__ O) {
  __shared__ unsigned short lA[128 * 32];
  __shared__ unsigned short lB[128 * 32];
  const int tid = threadIdx.x, lane = tid & 63, wave = tid >> 6;
  const int m0 = blockIdx.y * 128, n0 = blockIdx.x * 128;
  const int wm = (wave >> 1) * 64, wn = (wave & 1) * 64;
  floatx4 acc[4][4] = {};
  gemm_core(A, Bw, lA, lB, m0, n0, tid, lane, wave, acc);
#pragma unroll
  for (int mt = 0; mt < 4; ++mt)
#pragma unroll
    for (int nt = 0; nt < 4; ++nt)
#pragma unroll
      for (int r = 0; r < 4; ++r) {
        int row = m0 + wm + mt * 16 + (lane >> 4) * 4 + r;
        int col = n0 + wn + nt * 16 + (lane & 15);
        O[(size_t)row * D_ + col] = acc[mt][nt][r];
      }
}

// ---------------- Pass 1: Zl[b,q,k] = fp16( log2( sum_h exp2(s*C) ) ) ----------------
// 128x128 tiles (grid 16x16x2). No LDS, no barriers. (round-5 version, stable)
__launch_bounds__(256, 3)
__global__ void compute_z(const unsigned short* __restrict__ Qf,
                          const unsigned short* __restrict__ Kf,
                          unsigned short* __restrict__ Zl) {
  const int tid = threadIdx.x, lane = tid & 63, wave = tid >> 6;
  const int k0 = blockIdx.x * 128, q0 = blockIdx.y * 128, b = blockIdx.z;

  floatx4 zacc[2][8] = {};
  const short8* qbase = (const short8*)Qf + (size_t)b * H_ * (PERHEAD / 8)
                        + ((q0 >> 4) + wave * 2) * 128 + lane;
  const short8* kbase = (const short8*)Kf + (size_t)b * H_ * (PERHEAD / 8)
                        + (k0 >> 4) * 128 + lane;

#pragma unroll 1
  for (int h = 0; h < H_; ++h) {
    short8 qf0 = qbase[0], qf1 = qbase[64];
    short8 qf2 = qbase[128], qf3 = qbase[192];
#pragma unroll
    for (int hf = 0; hf < 2; ++hf) {
      short8 kst[4][2];
#pragma unroll
      for (int kb = 0; kb < 4; ++kb) {
        kst[kb][0] = kbase[(hf * 4 + kb) * 128];
        kst[kb][1] = kbase[(hf * 4 + kb) * 128 + 64];
      }
#pragma unroll
      for (int kb = 0; kb < 4; ++kb) {
        floatx4 s0 = {}, s1 = {};
        s0 = MFMA16(qf0, kst[kb][0], s0);
        s0 = MFMA16(qf1, kst[kb][1], s0);
        s1 = MFMA16(qf2, kst[kb][0], s1);
        s1 = MFMA16(qf3, kst[kb][1], s1);
#pragma unroll
        for (int r = 0; r < 4; ++r) {
          zacc[0][hf * 4 + kb][r] += exp2f(s0[r] * EXP2SCALE);
          zacc[1][hf * 4 + kb][r] += exp2f(s1[r] * EXP2SCALE);
        }
      }
    }
    qbase += PERHEAD / 8;
    kbase += PERHEAD / 8;
  }

#pragma unroll
  for (int sq = 0; sq < 2; ++sq)
#pragma unroll
    for (int kb = 0; kb < 8; ++kb)
#pragma unroll
      for (int r = 0; r < 4; ++r) {
        int q = q0 + wave * 32 + sq * 16 + (lane >> 4) * 4 + r;
        int k = k0 + kb * 16 + (lane & 15);
        union { _Float16 h; unsigned short u; } cv;
        cv.h = (_Float16)log2f(zacc[sq][kb][r]);
        Zl[((size_t)b * S_ + q) * S_ + k] = cv.u;
      }
}

// ---------------- Pass 2: x = exp2(s*C - Lz) @ V, BARRIER-FREE main loop ----------------
// Key identity: S^T's C-layout (lane: 4 consecutive keys at one q) IS the A-operand
// layout of v_mfma_f32_16x16x16f16 (A[m=lane&15][k=quad*4+j]). Each wave keeps its own
// 16 keys end-to-end: QK (K=32 bf16 MFMA) -> exp (in-lane) -> PV (K=16 f16 MFMA) with
// pre-laid-out Vg B-frags. No LDS, no barriers, no inter-wave exchange until a single
// fp32 LDS reduction epilogue (4 partial x's, 16KB chunked). Grid q-fastest for K/V L2 reuse.
__launch_bounds__(256, 2)
__global__ void attn_pv(const unsigned short* __restrict__ Qf,
                        const unsigned short* __restrict__ Kf,
                        const unsigned short* __restrict__ Vg,
                        const unsigned short* __restrict__ Zl,
                        unsigned short* __restrict__ X) {
  __shared__ float lR[4096];  // 16 KB epilogue reduction buffer (per-qb chunks)
  const int tid = threadIdx.x, lane = tid & 63, wave = tid >> 6;
  const int q0 = blockIdx.x * 64;
  const int h = blockIdx.y, b = blockIdx.z;

  const size_t headf = (size_t)(b * H_ + h) * (PERHEAD / 8);  // short8 units
  short8 qf[4][2];
#pragma unroll
  for (int qb = 0; qb < 4; ++qb) {
    const short8* qp = (const short8*)Qf + headf + ((q0 >> 4) + qb) * 128 + lane;
    qf[qb][0] = qp[0];
    qf[qb][1] = qp[64];
  }
  const short8* kp = (const short8*)Kf + headf + wave * 128 + lane;          // += 512/iter
  const uint2* vgp = (const uint2*)Vg + (size_t)(b * H_ + h) * (PERHEAD / 4)
                     + wave * 256 + lane;                                     // += 1024/iter
  const unsigned short* zp = Zl + ((size_t)b * S_ + q0 + (lane & 15)) * S_
                             + wave * 16 + ((lane >> 4) << 2);                // += 64/iter

  floatx4 xacc[4][4] = {};  // [qb][db]: partial x[q=qb*16+quad*4+r][dk=db*16+(lane&15)]

#pragma unroll 2
  for (int kt = 0; kt < S_ / 64; ++kt) {
    short8 ck0 = kp[0], ck1 = kp[64];
    uint2 vu0 = vgp[0], vu1 = vgp[64], vu2 = vgp[128], vu3 = vgp[192];
    uint2 zz0 = *(const uint2*)(zp);
    uint2 zz1 = *(const uint2*)(zp + (size_t)16 * S_);
    uint2 zz2 = *(const uint2*)(zp + (size_t)32 * S_);
    uint2 zz3 = *(const uint2*)(zp + (size_t)48 * S_);
    kp += 512; vgp += 1024; zp += 64;

    // S^T for this wave's 16 keys x 64 q
    floatx4 sacc[4] = {};
#pragma unroll
    for (int qb = 0; qb < 4; ++qb) {
      sacc[qb] = MFMA16(ck0, qf[qb][0], sacc[qb]);
      sacc[qb] = MFMA16(ck1, qf[qb][1], sacc[qb]);
    }

    union { uint2 u; half4_t h; } vh0, vh1, vh2, vh3;
    vh0.u = vu0; vh1.u = vu1; vh2.u = vu2; vh3.u = vu3;

#pragma unroll
    for (int qb = 0; qb < 4; ++qb) {
      uint2 zz = (qb == 0) ? zz0 : (qb == 1) ? zz1 : (qb == 2) ? zz2 : zz3;
      union { uint2 v; _Float16 hv[4]; } za; za.v = zz;
      float e0 = exp2f(fmaf(sacc[qb][0], EXP2SCALE, -(float)za.hv[0]));
      float e1 = exp2f(fmaf(sacc[qb][1], EXP2SCALE, -(float)za.hv[1]));
      float e2 = exp2f(fmaf(sacc[qb][2], EXP2SCALE, -(float)za.hv[2]));
      float e3 = exp2f(fmaf(sacc[qb][3], EXP2SCALE, -(float)za.hv[3]));
      union { fp16x2 h2[2]; half4_t h4; } pf;
      pf.h2[0] = __builtin_amdgcn_cvt_pkrtz(e0, e1);
      pf.h2[1] = __builtin_amdgcn_cvt_pkrtz(e2, e3);
      // P is already in A-layout for K=16 MFMA: m=q(lane&15), k=key(quad*4+j)
      xacc[qb][0] = MFMA16H(pf.h4, vh0.h, xacc[qb][0]);
      xacc[qb][1] = MFMA16H(pf.h4, vh1.h, xacc[qb][1]);
      xacc[qb][2] = MFMA16H(pf.h4, vh2.h, xacc[qb][2]);
      xacc[qb][3] = MFMA16H(pf.h4, vh3.h, xacc[qb][3]);
    }
  }

  // epilogue: sum the 4 waves' partial x via LDS (fp32), store bf16 to X[b,s,h*64+dk]
#pragma unroll 1
  for (int qb = 0; qb < 4; ++qb) {
#pragma unroll
    for (int db = 0; db < 4; ++db)
#pragma unroll
      for (int r = 0; r < 4; ++r) {
        int q16 = ((lane >> 4) << 2) + r;
        int dk = db * 16 + (lane & 15);
        lR[wave * 1024 + q16 * 64 + dk] = xacc[qb][db][r];
      }
    __syncthreads();
#pragma unroll
    for (int i = 0; i < 2; ++i) {
      int e = (i * 256 + tid) * 2;
      int q16 = e >> 6, dk = e & 63;
      float s0 = lR[e] + lR[1024 + e] + lR[2048 + e] + lR[3072 + e];
      float s1 = lR[e + 1] + lR[1024 + e + 1] + lR[2048 + e + 1] + lR[3072 + e + 1];
      unsigned int pk = pack_bf16_rhu(s0, s1);
      unsigned short* o = X + (size_t)(b * S_ + q0 + qb * 16 + q16) * D_ + h * DK_ + dk;
      *(unsigned int*)o = pk;
    }
    __syncthreads();
  }
}

// ---------------- launch ----------------
extern "C" void kernel_launch(void* const* d_in, const int* in_sizes, int n_in,
                              void* d_out, int out_size, void* d_ws, size_t ws_size,
                              hipStream_t stream) {
  const float* qi = (const float*)d_in[0];
  const float* ki = (const float*)d_in[1];
  const float* vi = (const float*)d_in[2];
  // d_in[3] = mask: reference discards masked_fill result -> unused
  const float* Wq = (const float*)d_in[4];
  const float* Wk = (const float*)d_in[5];
  const float* Wv = (const float*)d_in[6];
  const float* Wo = (const float*)d_in[7];

  const size_t NT = (size_t)B_ * S_ * D_;  // 4,194,304
  const size_t NW = (size_t)D_ * D_;       // 1,048,576

  unsigned short* w = (unsigned short*)d_ws;
  unsigned short* qi_bf = w; w += NT;
  unsigned short* ki_bf = w; w += NT;
  unsigned short* vi_bf = w; w += NT;
  unsigned short* Wq_bf = w; w += NW;
  unsigned short* Wk_bf = w; w += NW;
  unsigned short* Wv_bf = w; w += NW;
  unsigned short* Wo_bf = w; w += NW;
  unsigned short* Qf = w; w += NT;  // bf16 K=32 frags per (b,h)
  unsigned short* Kf = w; w += NT;
  unsigned short* Vg = w; w += NT;  // f16 K=16 B-frags per (b,h)
  unsigned short* Xb = w; w += NT;  // [b,s,e] row-major bf16
  unsigned short* Zl = w;           // [b,q,k] fp16 log2(Z), 16 MiB

  {
    int n4 = (int)(NT / 4);
    cast3_f32_bf16<<<dim3((n4 + 255) / 256, 1, 3), 256, 0, stream>>>(
        qi, ki, vi, qi_bf, ki_bf, vi_bf, n4);
    int n4w = (int)(NW / 4);
    cast4_f32_bf16<<<dim3((n4w + 255) / 256, 1, 4), 256, 0, stream>>>(
        Wq, Wk, Wv, Wo, Wq_bf, Wk_bf, Wv_bf, Wo_bf, n4w);
  }

  gemm_qkv<<<dim3(D_ / 128, (B_ * S_) / 128, 3), 256, 0, stream>>>(
      qi_bf, ki_bf, vi_bf, Wq_bf, Wk_bf, Wv_bf, Qf, Kf, Vg);

  compute_z<<<dim3(S_ / 128, S_ / 128, B_), 256, 0, stream>>>(Qf, Kf, Zl);
  attn_pv<<<dim3(S_ / 64, H_, B_), 256, 0, stream>>>(Qf, Kf, Vg, Zl, Xb);

  gemm_out<<<dim3(D_ / 128, (B_ * S_) / 128), 256, 0, stream>>>(Xb, Wo_bf, (float*)d_out);
}